// Round 3
// baseline (381.909 us; speedup 1.0000x reference)
//
#include <hip/hip_runtime.h>

#define NB 64
#define NN 1500
#define NM 100
#define NBINS 1280
#define KEEP 128

#define TOTALQ 9720000u        // float4 quads in out (38,880,000 floats / 4)
#define DELTA_FLOATS 31104000u
#define LOGIC_BLOCKS 64
#define FILL_BLOCKS 2048
#define GRID_TOTAL (LOGIC_BLOCKS + FILL_BLOCKS)

// ws layout (byte offsets): 0 flag(64B, memset to 0 each call) | 64 posCnt[64] |
// 320 negCnt[64] | 1024 posSlot[64*128] u32 | 33792 negSlot[64*128] u32 |
// 66560 posDD[64*128] float4  (total 197,632 B)

__global__ __launch_bounds__(256) void fused(
    const float4* __restrict__ roi, const float4* __restrict__ gt,
    const int* __restrict__ gtl, const int* __restrict__ rpos,
    const int* __restrict__ rneg, float* __restrict__ out,
    int* __restrict__ wsFlag, int* __restrict__ posCnt, int* __restrict__ negCnt,
    unsigned int* __restrict__ posSlot, unsigned int* __restrict__ negSlot,
    float4* __restrict__ posDD)
{
    __shared__ float4 gtb[NM];
    __shared__ float  gta[NM];
    __shared__ int sc[2][NN];
    __shared__ unsigned char kp[2][NN];
    __shared__ short bestS[NN];
    __shared__ int hist[NBINS];
    __shared__ int partial[256];
    __shared__ int wcnt[4];
    __shared__ int carry;
    __shared__ int sstar_s, q_s;
    __shared__ int cntLds[2];
    __shared__ int lastFlag;
    __shared__ int sP[NB], sN[NB];

    int blk = blockIdx.x;
    int tid = threadIdx.x;
    float4* outq = (float4*)out;

    if (blk < LOGIC_BLOCKS) {
        // ---------- per-batch IoU + argmax + masked scores (into LDS) ----------
        int b = blk;
        if (tid < NM) {
            float4 g = gt[b*NM + tid];
            gtb[tid] = g;
            gta[tid] = (g.z - g.x) * (g.w - g.y);
        }
        if (tid < 2) cntLds[tid] = 0;
        __syncthreads();
        for (int c = 0; c < 6; ++c) {
            int n = c*256 + tid;
            if (n < NN) {
                int idx = b*NN + n;
                float4 r = roi[idx];                   // [y1,x1,y2,x2]
                float by1=r.x, bx1=r.y, by2=r.z, bx2=r.w;
                float barea = (by2-by1)*(bx2-bx1);
                float bestIoU = -1.0f; int bestIdx = 0;
                for (int m = 0; m < NM; ++m) {
                    float4 g = gtb[m];
                    float xt = fmaxf(bx1, g.y);
                    float yt = fmaxf(by1, g.x);
                    float xb = fminf(bx2, g.w);
                    float yb = fminf(by2, g.z);
                    float inter = fmaxf(xb-xt, 0.0f) * fmaxf(yb-yt, 0.0f);
                    float uni = (barea + gta[m]) - inter;
                    float iou = inter / uni;
                    if (iou > bestIoU) { bestIoU = iou; bestIdx = m; } // first-max argmax
                }
                bestS[n] = (short)bestIdx;
                sc[0][n] = (bestIoU > 0.5f) ? rpos[idx] : 0;
                sc[1][n] = (bestIoU < 0.5f && bestIoU > 0.1f) ? rneg[idx] : 0;
            }
        }
        __syncthreads();

        // ---------- counting top-128 select (identical to passing version) ----------
        for (int m = 0; m < 2; ++m) {
            for (int s = tid; s < NBINS; s += 256) hist[s] = 0;
            if (tid == 0) { sstar_s = 0; q_s = 0; carry = 0; }
            __syncthreads();
            for (int i = tid; i < NN; i += 256) {
                int s = sc[m][i];
                if (s > 0) atomicAdd(&hist[s], 1);
            }
            __syncthreads();
            int base = tid*5;
            int p = hist[base]+hist[base+1]+hist[base+2]+hist[base+3]+hist[base+4];
            partial[tid] = p;
            __syncthreads();
            int myp = p;
            for (int off = 1; off < 256; off <<= 1) {
                int v = (tid + off < 256) ? partial[tid+off] : 0;
                __syncthreads();
                partial[tid] += v;
                __syncthreads();
            }
            int running = partial[tid] - myp;   // count strictly above my bins
            for (int s = base+4; s >= base; --s) {
                int c = hist[s];
                if (s >= 1 && c > 0 && running < KEEP && running + c >= KEEP) {
                    sstar_s = s; q_s = KEEP - running;     // straddle bin
                }
                running += c;
            }
            __syncthreads();
            int sstar = sstar_s, q = q_s;
            for (int c0 = 0; c0 < 6; ++c0) {   // ordered ballot-scan on ties
                int i = c0*256 + tid;
                int s = (i < NN) ? sc[m][i] : 0;
                bool eq = (s > 0) && (s == sstar);
                unsigned long long bal = __ballot(eq);
                int lane = tid & 63, w = tid >> 6;
                if (lane == 0) wcnt[w] = (int)__popcll(bal);
                __syncthreads();
                int pre = carry;
                for (int ww = 0; ww < w; ++ww) pre += wcnt[ww];
                int E = pre + (int)__popcll(bal & ((1ull << lane) - 1ull));
                bool keep = (i < NN) && (s > 0) && (s > sstar || (eq && E < q));
                if (i < NN) kp[m][i] = keep ? 1 : 0;
                __syncthreads();
                if (tid == 0) carry += wcnt[0]+wcnt[1]+wcnt[2]+wcnt[3];
                __syncthreads();
            }
        }
        __syncthreads();

        // ---------- build compact scatter lists ----------
        for (int i = tid; i < NN; i += 256) {
            int idx = b*NN + i;
            if (kp[0][i]) {
                int bi = bestS[i];
                int lab = gtl[b*NM + bi];
                float4 r = roi[idx];
                float4 g = gtb[bi];
                float bw = r.w - r.y, bh = r.z - r.x;
                float bcx = r.y + 0.5f*bw, bcy = r.x + 0.5f*bh;
                float gw = g.w - g.y, gh = g.z - g.x;
                float gcx = g.y + 0.5f*gw, gcy = g.x + 0.5f*gh;
                if (bw == 0.0f) bw = 0.001f;
                if (bh == 0.0f) bh = 0.001f;
                float dx  = (gw==0.0f) ? 0.0f : (gcx-bcx)/bw;
                float dy  = (gh==0.0f) ? 0.0f : (gcy-bcy)/bh;
                float dwv = (gw==0.0f) ? 0.0f : logf(gw/bw);
                float dhv = (gh==0.0f) ? 0.0f : logf(gh/bh);
                float4 dd = make_float4(dy/0.1f, dx/0.1f, dhv/0.2f, dwv/0.2f);
                int p = atomicAdd(&cntLds[0], 1);
                unsigned int slot = (unsigned int)idx * 81u + (unsigned int)lab;
                posSlot[b*KEEP + p] = slot;
                posDD[b*KEEP + p] = dd;
            } else if (kp[1][i]) {
                int p = atomicAdd(&cntLds[1], 1);
                negSlot[b*KEEP + p] = (unsigned int)idx * 81u;   // label 0
            }
        }
        __syncthreads();
        if (tid == 0) { posCnt[b] = cntLds[0]; negCnt[b] = cntLds[1]; }
    } else {
        // ---------- zero-fill of the whole output ----------
        unsigned int t = (unsigned int)(blk - LOGIC_BLOCKS) * 256u + (unsigned int)tid;
        const unsigned int stride = FILL_BLOCKS * 256u;
        const float4 z = make_float4(0.f, 0.f, 0.f, 0.f);
        for (unsigned int q = t; q < TOTALQ; q += stride) outq[q] = z;
    }

    // ---------- completion protocol: last block scatters ----------
    __threadfence();                 // release: flush this block's stores device-wide
    __syncthreads();
    if (tid == 0) {
        int old = atomicAdd(wsFlag, 1);
        __threadfence();             // acquire side of the RMW chain
        lastFlag = (old == GRID_TOTAL - 1) ? 1 : 0;
    }
    __syncthreads();
    if (lastFlag) {
        if (tid < NB) { sP[tid] = posCnt[tid]; sN[tid] = negCnt[tid]; }
        __syncthreads();
        for (int e = tid; e < NB*KEEP; e += 256) {
            int b = e >> 7;
            if ((e & 127) < sP[b]) {
                unsigned int s = posSlot[e];
                outq[s] = posDD[e];                 // delta quad
                out[DELTA_FLOATS + s] = 1.0f;       // one-hot label
            }
        }
        for (int e = tid; e < NB*KEEP; e += 256) {
            int b = e >> 7;
            if ((e & 127) < sN[b]) out[DELTA_FLOATS + negSlot[e]] = 1.0f;
        }
    }
}

extern "C" void kernel_launch(void* const* d_in, const int* in_sizes, int n_in,
                              void* d_out, int out_size, void* d_ws, size_t ws_size,
                              hipStream_t stream) {
    const float4* roi = (const float4*)d_in[0];   // [B,N,4] f32
    const float4* gt  = (const float4*)d_in[1];   // [B,M,4] f32
    const int* gtl  = (const int*)d_in[2];        // [B,M]
    const int* rpos = (const int*)d_in[3];        // [B,N]
    const int* rneg = (const int*)d_in[4];        // [B,N]
    float* out = (float*)d_out;

    char* ws = (char*)d_ws;
    int*          wsFlag  = (int*)(ws);
    int*          posCnt  = (int*)(ws + 64);
    int*          negCnt  = (int*)(ws + 320);
    unsigned int* posSlot = (unsigned int*)(ws + 1024);
    unsigned int* negSlot = (unsigned int*)(ws + 33792);
    float4*       posDD   = (float4*)(ws + 66560);

    hipMemsetAsync(wsFlag, 0, 64, stream);   // reset completion flag (graph-capturable)
    fused<<<GRID_TOTAL, 256, 0, stream>>>(roi, gt, gtl, rpos, rneg, out,
                                          wsFlag, posCnt, negCnt,
                                          posSlot, negSlot, posDD);
}

// Round 4
// 84.804 us; speedup vs baseline: 4.5034x; 4.5034x over previous
//
#include <hip/hip_runtime.h>

#define NB 64
#define NN 1500
#define NM 100
#define NBINS 1280
#define KEEP 128

#define TOTALQ 9720000u        // float4 quads in out (38,880,000 floats / 4)
#define DELTA_FLOATS 31104000u
#define LOGIC_BLOCKS 64
#define FILL_BLOCKS 2048
#define GRID_TOTAL (LOGIC_BLOCKS + FILL_BLOCKS)

// ws layout (byte offsets): 0 posCnt[64] | 256 negCnt[64] | 1024 posSlot[64*128] u32 |
// 33792 negSlot[64*128] u32 | 66560 posDD[64*128] float4   (total 197,632 B)

// ---------------- K1: logic blocks (selection -> ws) running concurrently with fill blocks ----------------
__global__ __launch_bounds__(256) void k1_fused(
    const float4* __restrict__ roi, const float4* __restrict__ gt,
    const int* __restrict__ gtl, const int* __restrict__ rpos,
    const int* __restrict__ rneg, float4* __restrict__ outq,
    int* __restrict__ posCnt, int* __restrict__ negCnt,
    unsigned int* __restrict__ posSlot, unsigned int* __restrict__ negSlot,
    float4* __restrict__ posDD)
{
    // LDS ~21 KB total (shared by both paths; keeps fill occupancy at 7 blocks/CU)
    __shared__ float4 gtb[NM];
    __shared__ float  gta[NM];
    __shared__ short  sc[2][NN];         // scores fit in short (< 1280)
    __shared__ unsigned char kp[2][NN];
    __shared__ short  bestS[NN];
    __shared__ int    hist[NBINS];
    __shared__ int    partial[256];
    __shared__ int    wcnt[4];
    __shared__ int    carry;
    __shared__ int    sstar_s, q_s;
    __shared__ int    cntLds[2];

    int blk = blockIdx.x;
    int tid = threadIdx.x;

    if (blk >= LOGIC_BLOCKS) {
        // ---------- pure zero-fill of the entire output; no fences, no atomics ----------
        unsigned int t = (unsigned int)(blk - LOGIC_BLOCKS) * 256u + (unsigned int)tid;
        const unsigned int stride = FILL_BLOCKS * 256u;
        const float4 z = make_float4(0.f, 0.f, 0.f, 0.f);
        for (unsigned int q = t; q < TOTALQ; q += stride) outq[q] = z;
        return;
    }

    // ---------- per-batch IoU + argmax + masked scores (into LDS) ----------
    int b = blk;
    if (tid < NM) {
        float4 g = gt[b*NM + tid];
        gtb[tid] = g;
        gta[tid] = (g.z - g.x) * (g.w - g.y);
    }
    if (tid < 2) cntLds[tid] = 0;
    __syncthreads();
    for (int c = 0; c < 6; ++c) {
        int n = c*256 + tid;
        if (n < NN) {
            int idx = b*NN + n;
            float4 r = roi[idx];                   // [y1,x1,y2,x2]
            float by1=r.x, bx1=r.y, by2=r.z, bx2=r.w;
            float barea = (by2-by1)*(bx2-bx1);
            float bestIoU = -1.0f; int bestIdx = 0;
            for (int m = 0; m < NM; ++m) {
                float4 g = gtb[m];
                float xt = fmaxf(bx1, g.y);
                float yt = fmaxf(by1, g.x);
                float xb = fminf(bx2, g.w);
                float yb = fminf(by2, g.z);
                float inter = fmaxf(xb-xt, 0.0f) * fmaxf(yb-yt, 0.0f);
                float uni = (barea + gta[m]) - inter;
                float iou = inter / uni;
                if (iou > bestIoU) { bestIoU = iou; bestIdx = m; } // first-max argmax
            }
            bestS[n] = (short)bestIdx;
            sc[0][n] = (short)((bestIoU > 0.5f) ? rpos[idx] : 0);
            sc[1][n] = (short)((bestIoU < 0.5f && bestIoU > 0.1f) ? rneg[idx] : 0);
        }
    }
    __syncthreads();

    // ---------- counting top-128 select (identical logic to passing versions) ----------
    for (int m = 0; m < 2; ++m) {
        for (int s = tid; s < NBINS; s += 256) hist[s] = 0;
        if (tid == 0) { sstar_s = 0; q_s = 0; carry = 0; }
        __syncthreads();
        for (int i = tid; i < NN; i += 256) {
            int s = sc[m][i];
            if (s > 0) atomicAdd(&hist[s], 1);
        }
        __syncthreads();
        int base = tid*5;
        int p = hist[base]+hist[base+1]+hist[base+2]+hist[base+3]+hist[base+4];
        partial[tid] = p;
        __syncthreads();
        int myp = p;
        for (int off = 1; off < 256; off <<= 1) {
            int v = (tid + off < 256) ? partial[tid+off] : 0;
            __syncthreads();
            partial[tid] += v;
            __syncthreads();
        }
        int running = partial[tid] - myp;   // count strictly above my bins
        for (int s = base+4; s >= base; --s) {
            int c = hist[s];
            if (s >= 1 && c > 0 && running < KEEP && running + c >= KEEP) {
                sstar_s = s; q_s = KEEP - running;     // straddle bin
            }
            running += c;
        }
        __syncthreads();
        int sstar = sstar_s, q = q_s;
        for (int c0 = 0; c0 < 6; ++c0) {   // ordered ballot-scan on ties
            int i = c0*256 + tid;
            int s = (i < NN) ? (int)sc[m][i] : 0;
            bool eq = (s > 0) && (s == sstar);
            unsigned long long bal = __ballot(eq);
            int lane = tid & 63, w = tid >> 6;
            if (lane == 0) wcnt[w] = (int)__popcll(bal);
            __syncthreads();
            int pre = carry;
            for (int ww = 0; ww < w; ++ww) pre += wcnt[ww];
            int E = pre + (int)__popcll(bal & ((1ull << lane) - 1ull));
            bool keep = (i < NN) && (s > 0) && (s > sstar || (eq && E < q));
            if (i < NN) kp[m][i] = keep ? 1 : 0;
            __syncthreads();
            if (tid == 0) carry += wcnt[0]+wcnt[1]+wcnt[2]+wcnt[3];
            __syncthreads();
        }
    }
    __syncthreads();

    // ---------- build compact scatter lists in ws (never touches out) ----------
    for (int i = tid; i < NN; i += 256) {
        int idx = b*NN + i;
        if (kp[0][i]) {
            int bi = bestS[i];
            int lab = gtl[b*NM + bi];
            float4 r = roi[idx];
            float4 g = gtb[bi];
            float bw = r.w - r.y, bh = r.z - r.x;
            float bcx = r.y + 0.5f*bw, bcy = r.x + 0.5f*bh;
            float gw = g.w - g.y, gh = g.z - g.x;
            float gcx = g.y + 0.5f*gw, gcy = g.x + 0.5f*gh;
            if (bw == 0.0f) bw = 0.001f;
            if (bh == 0.0f) bh = 0.001f;
            float dx  = (gw==0.0f) ? 0.0f : (gcx-bcx)/bw;
            float dy  = (gh==0.0f) ? 0.0f : (gcy-bcy)/bh;
            float dwv = (gw==0.0f) ? 0.0f : logf(gw/bw);
            float dhv = (gh==0.0f) ? 0.0f : logf(gh/bh);
            float4 dd = make_float4(dy/0.1f, dx/0.1f, dhv/0.2f, dwv/0.2f);
            int p = atomicAdd(&cntLds[0], 1);
            unsigned int slot = (unsigned int)idx * 81u + (unsigned int)lab;
            posSlot[b*KEEP + p] = slot;
            posDD[b*KEEP + p] = dd;
        } else if (kp[1][i]) {
            int p = atomicAdd(&cntLds[1], 1);
            negSlot[b*KEEP + p] = (unsigned int)idx * 81u;   // label 0
        }
    }
    __syncthreads();
    if (tid == 0) { posCnt[b] = cntLds[0]; negCnt[b] = cntLds[1]; }
}

// ---------------- K2: trivial sparse scatter (ordering via kernel boundary) ----------------
__global__ __launch_bounds__(256) void k2_scatter(
    const int* __restrict__ posCnt, const int* __restrict__ negCnt,
    const unsigned int* __restrict__ posSlot, const unsigned int* __restrict__ negSlot,
    const float4* __restrict__ posDD, float* __restrict__ out)
{
    int b = blockIdx.x;
    int t = threadIdx.x;
    if (t < KEEP) {
        if (t < posCnt[b]) {
            unsigned int s = posSlot[b*KEEP + t];
            reinterpret_cast<float4*>(out)[s] = posDD[b*KEEP + t];  // delta quad
            out[DELTA_FLOATS + s] = 1.0f;                           // one-hot label
        }
    } else {
        int u = t - KEEP;
        if (u < negCnt[b]) out[DELTA_FLOATS + negSlot[b*KEEP + u]] = 1.0f;
    }
}

extern "C" void kernel_launch(void* const* d_in, const int* in_sizes, int n_in,
                              void* d_out, int out_size, void* d_ws, size_t ws_size,
                              hipStream_t stream) {
    const float4* roi = (const float4*)d_in[0];   // [B,N,4] f32
    const float4* gt  = (const float4*)d_in[1];   // [B,M,4] f32
    const int* gtl  = (const int*)d_in[2];        // [B,M]
    const int* rpos = (const int*)d_in[3];        // [B,N]
    const int* rneg = (const int*)d_in[4];        // [B,N]
    float* out = (float*)d_out;

    char* ws = (char*)d_ws;
    int*          posCnt  = (int*)(ws);
    int*          negCnt  = (int*)(ws + 256);
    unsigned int* posSlot = (unsigned int*)(ws + 1024);
    unsigned int* negSlot = (unsigned int*)(ws + 33792);
    float4*       posDD   = (float4*)(ws + 66560);

    k1_fused <<<GRID_TOTAL, 256, 0, stream>>>(roi, gt, gtl, rpos, rneg,
                                              (float4*)out, posCnt, negCnt,
                                              posSlot, negSlot, posDD);
    k2_scatter<<<NB, 256, 0, stream>>>(posCnt, negCnt, posSlot, negSlot, posDD, out);
}